// Round 16
// baseline (441.359 us; speedup 1.0000x reference)
//
#include <hip/hip_runtime.h>
#include <hip/hip_bf16.h>
#include <math.h>

// Problem constants
#define S 2048
#define H 1024
#define NE 8
#define INTER 2048
#define ALPHA 1.702f
#define LIMIT 7.0f

typedef __bf16 bf16x8 __attribute__((ext_vector_type(8)));
typedef float f32x4 __attribute__((ext_vector_type(4)));

// Workspace layout (bytes) -- no weight repack pass: GEMMs consume fp32
// weights directly.
#define WS_COUNTS 0                                   // 4 KB
#define WS_SLOTS  4096                                // int[NE][S] = 64 KB
#define WS_W      (WS_SLOTS + NE*S*4)                 // float[2S] = 16 KB
#define WS_XB     (WS_W + 2*S*4)                      // bf16 x [S][H] = 4 MB
#define WS_ACT    (WS_XB + (size_t)S*H*2)             // bf16 [2S][I] = 16 MB

static __device__ __forceinline__ unsigned short f2bf(float f) {
    union { __hip_bfloat16 h; unsigned short u; } cv;
    cv.h = __float2bfloat16(f);
    return cv.u;
}

static __device__ __forceinline__ void gload16(const void* g, void* l) {
    __builtin_amdgcn_global_load_lds(
        (const __attribute__((address_space(1))) unsigned int*)(unsigned long long)g,
        (__attribute__((address_space(3))) unsigned int*)(unsigned int)(unsigned long long)l,
        16, 0, 0);
}

// LDS-only barrier (no vmcnt drain).
static __device__ __forceinline__ void ldsbar() {
    asm volatile("s_waitcnt lgkmcnt(0)" ::: "memory");
    __builtin_amdgcn_s_barrier();
}

// chunk-shift for the fp32-tile column rotation: s(q) = {0,4,1,5}[q]
static __device__ __forceinline__ int sshift(int q) {
    return (q >> 1) + ((q & 1) << 2);
}

// ---------------------------------------------------------------------------
// Router + x->bf16 conversion. One wave per token.
// ---------------------------------------------------------------------------
__global__ __launch_bounds__(64) void router_conv(
    const float* __restrict__ x, const float* __restrict__ rw,
    const float* __restrict__ rb, int* __restrict__ counts,
    int* __restrict__ slots, float* __restrict__ slot_w,
    unsigned short* __restrict__ xb)
{
    int tok = blockIdx.x;
    int lane = threadIdx.x;
    const float4* xr = (const float4*)(x + (size_t)tok * H);
    ushort4* xo = (ushort4*)(xb + (size_t)tok * H);
    float acc[NE];
#pragma unroll
    for (int e = 0; e < NE; ++e) acc[e] = 0.f;
#pragma unroll
    for (int p = 0; p < H / 256; ++p) {
        int idx = p * 64 + lane;
        float4 v = xr[idx];
        ushort4 o;
        o.x = f2bf(v.x); o.y = f2bf(v.y); o.z = f2bf(v.z); o.w = f2bf(v.w);
        xo[idx] = o;
        const float* wr = rw + (size_t)idx * 4 * NE;
#pragma unroll
        for (int e = 0; e < NE; ++e)
            acc[e] += v.x * wr[e] + v.y * wr[NE + e] + v.z * wr[2 * NE + e] + v.w * wr[3 * NE + e];
    }
#pragma unroll
    for (int e = 0; e < NE; ++e) {
#pragma unroll
        for (int off = 32; off > 0; off >>= 1)
            acc[e] += __shfl_down(acc[e], off);
    }
    if (lane == 0) {
        float v[NE];
#pragma unroll
        for (int e = 0; e < NE; ++e) v[e] = acc[e] + rb[e];
        int i1 = 0; float v1 = v[0];
#pragma unroll
        for (int e = 1; e < NE; ++e) if (v[e] > v1) { v1 = v[e]; i1 = e; }
        int i2 = -1; float v2 = -3.0e38f;
#pragma unroll
        for (int e = 0; e < NE; ++e) if (e != i1 && v[e] > v2) { v2 = v[e]; i2 = e; }
        float w1 = 1.f / (1.f + expf(v2 - v1));
        float w2 = 1.f - w1;
        int p1 = atomicAdd(&counts[i1], 1);
        slots[i1 * S + p1] = tok * 2;
        slot_w[tok * 2] = w1;
        int p2 = atomicAdd(&counts[i2], 1);
        slots[i2 * S + p2] = tok * 2 + 1;
        slot_w[tok * 2 + 1] = w2;
    }
}

// ---------------------------------------------------------------------------
// Grouped gate_up MFMA GEMM, fp32 weights consumed directly, two-stage LDS:
//   1) gload16 fp32 [32k][64n] tile, columns ROTATED per k-octet via
//      pre-swizzled GLOBAL source (stored col = n + {0,16,4,20}[k>>3] mod 64)
//   2) convert phase: thread (rn=t>>2, rk=(t&3)*8) reads its k-octet column
//      (bank = (rn+off)%32 -- exactly 2 lanes/bank, free), casts to bf16,
//      writes u16x8 to bf16 [64n][32k] tile (8-deep b128 minimum)
//   3) fragments via ds_read_b128 (the proven round-0..14 pattern)
// Replaces round-15's 32x 4-way-conflicted scalar reads + 32 casts per
// thread/iter (11.8M conflict cycles measured) with 16 free reads + 16 casts.
// ---------------------------------------------------------------------------
__global__ __launch_bounds__(256) void gateup_mfma(
    const unsigned short* __restrict__ xb,
    const float* __restrict__ gup,
    const float* __restrict__ gub,
    const int* __restrict__ counts, const int* __restrict__ slots,
    unsigned short* __restrict__ act)
{
    int e = blockIdx.z;
    int cnt = counts[e];
    int m0 = blockIdx.y * 128;
    if (m0 >= cnt) return;
    int n0 = blockIdx.x * 64;

    __shared__ unsigned short As[128 * 32];   // bf16 [128m][32k]
    __shared__ float Gf[32 * 64];             // fp32 [32k][64n] (rotated cols)
    __shared__ float Uf[32 * 64];
    __shared__ unsigned short Gb[64 * 32];    // bf16 [64n][32k]
    __shared__ unsigned short Ub[64 * 32];
    __shared__ int sl[128];

    int t = threadIdx.x;
    int lane = t & 63, w = t >> 6;
    if (t < 128) {
        int r = m0 + t;
        sl[t] = slots[e * S + (r < cnt ? r : cnt - 1)];
    }
    __syncthreads();

    int quad = lane >> 4, l16 = lane & 15;
    int wm = (w >> 1) * 64, wn = (w & 1) * 32;

    // A staging (bf16 tokens, unchanged)
    int ar0 = w * 32 + (lane >> 2);
    int ar1 = ar0 + 16;
    const unsigned short* ap0 = xb + (size_t)(sl[ar0] >> 1) * H + (lane & 3) * 8;
    const unsigned short* ap1 = xb + (size_t)(sl[ar1] >> 1) * H + (lane & 3) * 8;
    unsigned short* la0 = &As[(2 * w) * 512 + lane * 8];
    unsigned short* la1 = &As[(2 * w + 1) * 512 + lane * 8];

    // B staging: thread t owns fp32-tile slot (row t>>4, chunk t&15).
    // Global source pre-swizzled so stored chunk c holds logical (c - s_q)&15.
    int brow = t >> 4, bc = t & 15;
    int sq0 = sshift(brow >> 3);          // rows 0..15  -> q in {0,1}
    int sq1 = sshift((brow + 16) >> 3);   // rows 16..31 -> q in {2,3}
    const float* base = gup + (size_t)e * H * 2 * INTER + n0;
    const float* gsrc0 = base + (size_t)brow * (2 * INTER) + ((bc - sq0) & 15) * 4;
    const float* gsrc1 = base + (size_t)(brow + 16) * (2 * INTER) + ((bc - sq1) & 15) * 4;
    const float* usrc0 = gsrc0 + INTER;
    const float* usrc1 = gsrc1 + INTER;
    float* lgf0 = &Gf[t * 4];
    float* lgf1 = &Gf[1024 + t * 4];
    float* luf0 = &Uf[t * 4];
    float* luf1 = &Uf[1024 + t * 4];

    // convert-phase geometry: thread (rn = t>>2, rk = (t&3)*8)
    int rn = t >> 2, rkc = (t & 3) * 8;
    int rnp = (rn + 4 * sshift(t & 3)) & 63;   // stored column of logical rn

    f32x4 accg[4][2], accu[4][2];
#pragma unroll
    for (int mi = 0; mi < 4; ++mi)
#pragma unroll
        for (int ni = 0; ni < 2; ++ni) {
            accg[mi][ni] = (f32x4){0.f, 0.f, 0.f, 0.f};
            accu[mi][ni] = (f32x4){0.f, 0.f, 0.f, 0.f};
        }

    for (int k0 = 0; k0 < H; k0 += 32) {
        ldsbar();                      // protect tiles (LDS-only, no vm drain)
        gload16(ap0 + k0, la0);
        gload16(ap1 + k0, la1);
        size_t ko = (size_t)k0 * 2 * INTER;
        gload16(gsrc0 + ko, lgf0);
        gload16(gsrc1 + ko, lgf1);
        gload16(usrc0 + ko, luf0);
        gload16(usrc1 + ko, luf1);
        __syncthreads();               // drains vmcnt: staged data landed

        // convert: fp32 tile -> bf16 [n][k] tile
        {
            union { bf16x8 v; __bf16 e8[8]; } cg, cu;
#pragma unroll
            for (int i = 0; i < 8; ++i) {
                cg.e8[i] = (__bf16)Gf[(rkc + i) * 64 + rnp];
                cu.e8[i] = (__bf16)Uf[(rkc + i) * 64 + rnp];
            }
            *(bf16x8*)&Gb[rn * 32 + rkc] = cg.v;
            *(bf16x8*)&Ub[rn * 32 + rkc] = cu.v;
        }
        ldsbar();                      // converted tiles visible

        bf16x8 af[4], gf[2], uf[2];
#pragma unroll
        for (int mi = 0; mi < 4; ++mi)
            af[mi] = *(const bf16x8*)&As[(wm + mi * 16 + l16) * 32 + quad * 8];
#pragma unroll
        for (int ni = 0; ni < 2; ++ni) {
            int n = wn + ni * 16 + l16;
            gf[ni] = *(const bf16x8*)&Gb[n * 32 + quad * 8];
            uf[ni] = *(const bf16x8*)&Ub[n * 32 + quad * 8];
        }
#pragma unroll
        for (int mi = 0; mi < 4; ++mi)
#pragma unroll
            for (int ni = 0; ni < 2; ++ni) {
                accg[mi][ni] = __builtin_amdgcn_mfma_f32_16x16x32_bf16(af[mi], gf[ni], accg[mi][ni], 0, 0, 0);
                accu[mi][ni] = __builtin_amdgcn_mfma_f32_16x16x32_bf16(af[mi], uf[ni], accu[mi][ni], 0, 0, 0);
            }
    }

    const float* gb = gub + (size_t)e * 2 * INTER;
#pragma unroll
    for (int mi = 0; mi < 4; ++mi) {
#pragma unroll
        for (int r = 0; r < 4; ++r) {
            int rt = wm + mi * 16 + quad * 4 + r;
            if (m0 + rt >= cnt) continue;
            int slot = sl[rt];
            unsigned short* orow = act + (size_t)slot * INTER;
#pragma unroll
            for (int ni = 0; ni < 2; ++ni) {
                int col = n0 + wn + ni * 16 + l16;
                float gate = accg[mi][ni][r] + gb[col];
                float uv = accu[mi][ni][r] + gb[INTER + col];
                gate = fminf(gate, LIMIT);
                uv = fminf(fmaxf(uv, -LIMIT), LIMIT);
                float glu = gate / (1.f + __expf(-ALPHA * gate));
                orow[col] = f2bf((uv + 1.f) * glu);
            }
        }
    }
}

// ---------------------------------------------------------------------------
// Grouped down MFMA GEMM, fp32 weights direct, same two-stage convert.
// K-split 2 (grid.z = e*2+ks).
// ---------------------------------------------------------------------------
__global__ __launch_bounds__(256) void down_mfma(
    const unsigned short* __restrict__ act,
    const float* __restrict__ dp,
    const float* __restrict__ db,
    const int* __restrict__ counts, const int* __restrict__ slots,
    const float* __restrict__ slot_w,
    float* __restrict__ out)
{
    int e = blockIdx.z >> 1;
    int ks = blockIdx.z & 1;
    int cnt = counts[e];
    int m0 = blockIdx.y * 128;
    if (m0 >= cnt) return;
    int n0 = blockIdx.x * 64;

    __shared__ unsigned short As[128 * 32];
    __shared__ float Bf[32 * 64];
    __shared__ unsigned short Bb[64 * 32];
    __shared__ int sl[128];

    int t = threadIdx.x;
    int lane = t & 63, w = t >> 6;
    if (t < 128) {
        int r = m0 + t;
        sl[t] = slots[e * S + (r < cnt ? r : cnt - 1)];
    }
    __syncthreads();

    int quad = lane >> 4, l16 = lane & 15;
    int wm = (w >> 1) * 64, wn = (w & 1) * 32;

    int ar0 = w * 32 + (lane >> 2);
    int ar1 = ar0 + 16;
    int kbase = ks * (INTER / 2);
    const unsigned short* ap0 = act + (size_t)sl[ar0] * INTER + kbase + (lane & 3) * 8;
    const unsigned short* ap1 = act + (size_t)sl[ar1] * INTER + kbase + (lane & 3) * 8;
    unsigned short* la0 = &As[(2 * w) * 512 + lane * 8];
    unsigned short* la1 = &As[(2 * w + 1) * 512 + lane * 8];

    int brow = t >> 4, bc = t & 15;
    int sq0 = sshift(brow >> 3);
    int sq1 = sshift((brow + 16) >> 3);
    const float* base = dp + (size_t)e * INTER * H + n0;
    const float* bsrc0 = base + (size_t)(kbase + brow) * H + ((bc - sq0) & 15) * 4;
    const float* bsrc1 = base + (size_t)(kbase + brow + 16) * H + ((bc - sq1) & 15) * 4;
    float* lbf0 = &Bf[t * 4];
    float* lbf1 = &Bf[1024 + t * 4];

    int rn = t >> 2, rkc = (t & 3) * 8;
    int rnp = (rn + 4 * sshift(t & 3)) & 63;

    f32x4 acc[4][2];
#pragma unroll
    for (int mi = 0; mi < 4; ++mi)
#pragma unroll
        for (int ni = 0; ni < 2; ++ni)
            acc[mi][ni] = (f32x4){0.f, 0.f, 0.f, 0.f};

    for (int k0 = 0; k0 < INTER / 2; k0 += 32) {
        ldsbar();
        gload16(ap0 + k0, la0);
        gload16(ap1 + k0, la1);
        size_t ko = (size_t)k0 * H;
        gload16(bsrc0 + ko, lbf0);
        gload16(bsrc1 + ko, lbf1);
        __syncthreads();

        {
            union { bf16x8 v; __bf16 e8[8]; } cb;
#pragma unroll
            for (int i = 0; i < 8; ++i)
                cb.e8[i] = (__bf16)Bf[(rkc + i) * 64 + rnp];
            *(bf16x8*)&Bb[rn * 32 + rkc] = cb.v;
        }
        ldsbar();

        bf16x8 af[4], bf[2];
#pragma unroll
        for (int mi = 0; mi < 4; ++mi)
            af[mi] = *(const bf16x8*)&As[(wm + mi * 16 + l16) * 32 + quad * 8];
#pragma unroll
        for (int ni = 0; ni < 2; ++ni) {
            int n = wn + ni * 16 + l16;
            bf[ni] = *(const bf16x8*)&Bb[n * 32 + quad * 8];
        }
#pragma unroll
        for (int mi = 0; mi < 4; ++mi)
#pragma unroll
            for (int ni = 0; ni < 2; ++ni)
                acc[mi][ni] = __builtin_amdgcn_mfma_f32_16x16x32_bf16(af[mi], bf[ni], acc[mi][ni], 0, 0, 0);
    }

    const float* dbr = db + (size_t)e * H;
#pragma unroll
    for (int mi = 0; mi < 4; ++mi) {
#pragma unroll
        for (int r = 0; r < 4; ++r) {
            int rt = wm + mi * 16 + quad * 4 + r;
            if (m0 + rt >= cnt) continue;
            int slot = sl[rt];
            int tok = slot >> 1;
            float wgt = slot_w[slot];
#pragma unroll
            for (int ni = 0; ni < 2; ++ni) {
                int col = n0 + wn + ni * 16 + l16;
                float rr = acc[mi][ni][r] + (ks == 0 ? dbr[col] : 0.f);
                atomicAdd(&out[(size_t)tok * H + col], wgt * rr);
            }
        }
    }
}

// ---------------------------------------------------------------------------
extern "C" void kernel_launch(void* const* d_in, const int* in_sizes, int n_in,
                              void* d_out, int out_size, void* d_ws, size_t ws_size,
                              hipStream_t stream)
{
    const float* x   = (const float*)d_in[0];
    const float* rw  = (const float*)d_in[1];
    const float* rb  = (const float*)d_in[2];
    const float* gup = (const float*)d_in[3];
    const float* gub = (const float*)d_in[4];
    const float* dp  = (const float*)d_in[5];
    const float* db  = (const float*)d_in[6];
    float* out = (float*)d_out;

    char* ws = (char*)d_ws;
    int* counts            = (int*)(ws + WS_COUNTS);
    int* slots             = (int*)(ws + WS_SLOTS);
    float* slot_w          = (float*)(ws + WS_W);
    unsigned short* xb     = (unsigned short*)(ws + WS_XB);
    unsigned short* act    = (unsigned short*)(ws + WS_ACT);

    hipMemsetAsync(counts, 0, 4096, stream);
    hipMemsetAsync(out, 0, (size_t)S * H * sizeof(float), stream);

    router_conv<<<S, 64, 0, stream>>>(x, rw, rb, counts, slots, slot_w, xb);

    gateup_mfma<<<dim3(INTER / 64, 16, NE), 256, 0, stream>>>(
        xb, gup, gub, counts, slots, act);

    down_mfma<<<dim3(H / 64, 16, NE * 2), 256, 0, stream>>>(
        act, dp, db, counts, slots, slot_w, out);
}